// Round 7
// baseline (140.057 us; speedup 1.0000x reference)
//
#include <hip/hip_runtime.h>
#include <hip/hip_bf16.h>

// Problem constants
#define NB   4      // batch
#define CCH  3      // channels
#define HW   320    // height == width
#define KS   5      // kernel/stride
#define LP   4096   // patches per batch (64*64)
#define KD   75     // c*k*k
#define NCH  12     // 16B chunks per patch row (96 bf16 = 12 x 8)

typedef __attribute__((ext_vector_type(4))) float f32x4;
typedef __attribute__((ext_vector_type(8))) short bf16x8;

__device__ __forceinline__ ushort f2bf(float v) {
    __hip_bfloat16 h = __float2bfloat16(v);
    return __builtin_bit_cast(ushort, h);
}

// Kernel 1: per-patch sumsq from x (fp32), block-max over 4 patches, one
// device-scope atomicMax per block onto maxbits[b] (float bits, all >= 0).
__global__ __launch_bounds__(256) void norm_kernel(const float* __restrict__ x,
                                                   unsigned* __restrict__ maxbits) {
    int tid  = threadIdx.x;
    int lane = tid & 63;
    int pid  = blockIdx.x * 4 + (tid >> 6);   // 0..16383
    int b    = pid >> 12;
    int pp   = pid & 4095;
    int ph   = pp >> 6, pw = pp & 63;
    const float* xb = x + (size_t)b * (CCH * HW * HW);
    int row0 = ph * KS, col0 = pw * KS;

    float ss = 0.f;
    for (int k = lane; k < KD; k += 64) {
        int c = k / 25, rem = k % 25;
        int ki = rem / 5, kj = rem % 5;
        float v = xb[(c * HW + row0 + ki) * HW + col0 + kj];
        ss += v * v;
    }
    for (int off = 32; off; off >>= 1) ss += __shfl_xor(ss, off, 64);

    __shared__ float sm[4];
    if (lane == 0) sm[tid >> 6] = ss;
    __syncthreads();
    if (tid == 0) {
        float m = fmaxf(fmaxf(sm[0], sm[1]), fmaxf(sm[2], sm[3]));
        atomicMax(maxbits + b, __float_as_uint(m));   // non-negative: bit order == float order
    }
}

// Kernel 2: build bf16 patch matrix in fragment-blocked layout
// p2[b][chunk][row] of 16B (8 bf16): chunk c holds patch cols 8c..8c+7
// (zero-padded past KD=75). Fully written every call (chunks 10,11 = zeros).
__global__ __launch_bounds__(256) void patch_kernel(const float* __restrict__ x,
                                                    ushort* __restrict__ p2) {
    int tid = threadIdx.x;
    int r   = blockIdx.x * 256 + tid;    // patch row 0..4095
    int c   = blockIdx.y;                // chunk 0..11
    int b   = blockIdx.z;
    int ph = r >> 6, pw = r & 63;
    const float* xb = x + (size_t)b * (CCH * HW * HW);

    bf16x8 v = {};
    if (c < 10) {
        #pragma unroll
        for (int j = 0; j < 8; ++j) {
            int k = c * 8 + j;
            float f = 0.f;
            if (k < KD) {
                int ch = k / 25, rem = k % 25;
                int ki = rem / 5, kj = rem % 5;
                f = xb[(ch * HW + ph * KS + ki) * HW + pw * KS + kj];
            }
            v[j] = (short)f2bf(f);
        }
    }
    *(bf16x8*)&p2[((size_t)(b * NCH + c) * LP + r) * 8] = v;
}

// Kernel 3 (stripe blocks): each block computes a 16-row x 4096-col stripe of
// C = sigmoid((P P^T)/sqrt(max_sumsq)) -> its write region is one CONTIGUOUS
// 256KB span (fill-like DRAM access). 4 waves; per step each wave does
// 16x64 out: 12 B-frag loads (L2-resident p2), 12 MFMA with SWAPPED operands
// (D rows = i = contiguous store dir), sigmoid, per-wave swizzled LDS restage
// (no barriers), 4 NT stores of 4x256B full-line runs. 16 steps cover 4096.
__global__ __launch_bounds__(256) void gemm_kernel(const ushort* __restrict__ p2,
                                                   const unsigned* __restrict__ maxbits,
                                                   float* __restrict__ out) {
    __shared__ float W[4][16][64];     // per-wave restage buffer (swizzled 16B slots)

    int b      = blockIdx.y;
    int stripe = blockIdx.x;           // 0..255
    int j0     = stripe * 16;
    int tid  = threadIdx.x;
    int lane = tid & 63;
    int w    = tid >> 6;               // wave = i-group within a step
    int lrow = lane & 15;
    int lch  = lane >> 4;

    const ushort* pb = p2 + (size_t)b * NCH * LP * 8;

    // Preload stripe (j-side) fragments: used as SECOND MFMA operand.
    bf16x8 a[3];
    #pragma unroll
    for (int ks = 0; ks < 3; ++ks)
        a[ks] = *(const bf16x8*)&pb[((size_t)(ks * 4 + lch) * LP + j0 + lrow) * 8];

    float inv = 1.0f / sqrtf(__uint_as_float(maxbits[b]));
    float* ob = out + (size_t)b * LP * LP;
    float* Wp = &W[w][0][0];

    for (int s = 0; s < 16; ++s) {
        int i0 = s * 256 + w * 64;

        // i-side fragments (FIRST operand): rows i0+n*16+lrow, plane ks*4+lch
        bf16x8 bn[4][3];
        #pragma unroll
        for (int n = 0; n < 4; ++n)
            #pragma unroll
            for (int ks = 0; ks < 3; ++ks)
                bn[n][ks] = *(const bf16x8*)&pb[((size_t)(ks * 4 + lch) * LP + i0 + n * 16 + lrow) * 8];

        // D[row=i_local][col=j_local]; value = dot(p_i, p_j) = C[j][i] exactly.
        f32x4 acc[4] = {};
        #pragma unroll
        for (int ks = 0; ks < 3; ++ks)
            #pragma unroll
            for (int n = 0; n < 4; ++n)
                acc[n] = __builtin_amdgcn_mfma_f32_16x16x32_bf16(bn[n][ks], a[ks], acc[n], 0, 0, 0);

        // scatter into swizzled LDS: W[j][slot^j]; thread holds i_local =
        // n*16+lch*4+r (contiguous over r) for j_local = lane&15.
        #pragma unroll
        for (int n = 0; n < 4; ++n) {
            int sl = (n * 4 + lch) ^ lrow;         // 16B slot, swizzled by j-row
            f32x4 v;
            #pragma unroll
            for (int r = 0; r < 4; ++r) {
                float t = acc[n][r] * inv;
                v[r] = 1.0f / (1.0f + __expf(-t));
            }
            *(f32x4*)&Wp[lrow * 64 + sl * 4] = v;
        }
        // gather rows linearly; 4 rows x 256B full-line runs per store instr
        #pragma unroll
        for (int k = 0; k < 4; ++k) {
            int jr = k * 4 + lch;                  // j_local 0..15
            int sl = lrow ^ jr;                    // inverse swizzle
            f32x4 v = *(const f32x4*)&Wp[jr * 64 + sl * 4];
            __builtin_nontemporal_store(v, (f32x4*)&ob[(size_t)(j0 + jr) * LP + i0 + lrow * 4]);
        }
    }
}

extern "C" void kernel_launch(void* const* d_in, const int* in_sizes, int n_in,
                              void* d_out, int out_size, void* d_ws, size_t ws_size,
                              hipStream_t stream) {
    const float* x = (const float*)d_in[0];
    float* out = (float*)d_out;

    // ws layout: p2 bf16 blocked [NB][12][4096][8] (3.15 MB), then maxbits[4].
    ushort* p2 = (ushort*)d_ws;
    unsigned* maxbits = (unsigned*)((char*)d_ws + (size_t)NB * NCH * LP * 16);

    hipMemsetAsync(maxbits, 0, NB * sizeof(unsigned), stream);   // capture-legal
    norm_kernel<<<(NB * LP) / 4, 256, 0, stream>>>(x, maxbits);
    patch_kernel<<<dim3(LP / 256, NCH, NB), 256, 0, stream>>>(x, p2);
    gemm_kernel<<<dim3(LP / 16, NB), 256, 0, stream>>>(p2, maxbits, out);
}

// Round 10
// 110.502 us; speedup vs baseline: 1.2675x; 1.2675x over previous
//
#include <hip/hip_runtime.h>
#include <hip/hip_bf16.h>

// Problem constants
#define NB   4      // batch
#define CCH  3      // channels
#define HW   320    // height == width
#define KS   5      // kernel/stride
#define LP   4096   // patches per batch (64*64)
#define KD   75     // c*k*k
#define NCH  12     // 16B chunks per patch row (96 bf16 = 12 x 8)

typedef __attribute__((ext_vector_type(4))) float f32x4;
typedef __attribute__((ext_vector_type(8))) short bf16x8;

__device__ __forceinline__ ushort f2bf(float v) {
    __hip_bfloat16 h = __float2bfloat16(v);
    return __builtin_bit_cast(ushort, h);
}

// Kernel 1: per-patch sumsq from x (fp32), block-max over 4 patches, one
// device-scope atomicMax per block onto maxbits[b] (float bits, all >= 0).
__global__ __launch_bounds__(256) void norm_kernel(const float* __restrict__ x,
                                                   unsigned* __restrict__ maxbits) {
    int tid  = threadIdx.x;
    int lane = tid & 63;
    int pid  = blockIdx.x * 4 + (tid >> 6);   // 0..16383
    int b    = pid >> 12;
    int pp   = pid & 4095;
    int ph   = pp >> 6, pw = pp & 63;
    const float* xb = x + (size_t)b * (CCH * HW * HW);
    int row0 = ph * KS, col0 = pw * KS;

    float ss = 0.f;
    for (int k = lane; k < KD; k += 64) {
        int c = k / 25, rem = k % 25;
        int ki = rem / 5, kj = rem % 5;
        float v = xb[(c * HW + row0 + ki) * HW + col0 + kj];
        ss += v * v;
    }
    for (int off = 32; off; off >>= 1) ss += __shfl_xor(ss, off, 64);

    __shared__ float sm[4];
    if (lane == 0) sm[tid >> 6] = ss;
    __syncthreads();
    if (tid == 0) {
        float m = fmaxf(fmaxf(sm[0], sm[1]), fmaxf(sm[2], sm[3]));
        atomicMax(maxbits + b, __float_as_uint(m));   // non-negative: bit order == float order
    }
}

// Kernel 2: build bf16 patch matrix in fragment-blocked layout
// p2[b][chunk][row] of 16B (8 bf16): chunk c holds patch cols 8c..8c+7
// (zero-padded past KD=75). Fully written every call (chunks 10,11 = zeros).
__global__ __launch_bounds__(256) void patch_kernel(const float* __restrict__ x,
                                                    ushort* __restrict__ p2) {
    int tid = threadIdx.x;
    int r   = blockIdx.x * 256 + tid;    // patch row 0..4095
    int c   = blockIdx.y;                // chunk 0..11
    int b   = blockIdx.z;
    int ph = r >> 6, pw = r & 63;
    const float* xb = x + (size_t)b * (CCH * HW * HW);

    bf16x8 v = {};
    if (c < 10) {
        #pragma unroll
        for (int j = 0; j < 8; ++j) {
            int k = c * 8 + j;
            float f = 0.f;
            if (k < KD) {
                int ch = k / 25, rem = k % 25;
                int ki = rem / 5, kj = rem % 5;
                f = xb[(ch * HW + ph * KS + ki) * HW + pw * KS + kj];
            }
            v[j] = (short)f2bf(f);
        }
    }
    *(bf16x8*)&p2[((size_t)(b * NCH + c) * LP + r) * 8] = v;
}

// Kernel 3: per batch C = sigmoid((P P^T) / sqrt(max_sumsq)), 128x128 tile
// per block, fragments read directly from blocked p2 (coalesced, L2-resident).
// 4 waves 2x2, each 64x64 out. Epilogue: per-wave LDS restage (double-buffered
// by n-parity, swizzled, no barriers) -> every store instr writes 4x256B
// full-line runs, nontemporal. Output stored transposed (C symmetric, MFMA
// k-order identical for (i,j)/(j,i) -> bit-identical).
// DISPATCH-ORDER NOTE: blockIdx.x (fastest) = tr sweeps output COLUMNS within
// one 128-out-row band (tc = blockIdx.y); the ~2000 concurrently-resident
// blocks then write a narrow (~32MB) advancing address window, fill-like,
// instead of scattering over the whole 64MB batch slab (page-miss drain).
__global__ __launch_bounds__(256) void gemm_kernel(const ushort* __restrict__ p2,
                                                   const unsigned* __restrict__ maxbits,
                                                   float* __restrict__ out) {
    __shared__ float W[4][2][16][64];  // per-wave, double-buffered restage

    int b  = blockIdx.z;
    int tr = blockIdx.x;   // i-tiles: FAST dispatch dim (output col sweep)
    int tc = blockIdx.y;   // j-tiles: out-row band (slow dim)
    int tid = threadIdx.x;
    int lane = tid & 63;
    int w  = tid >> 6;
    int wr = w >> 1, wc = w & 1;        // 2x2 wave grid, each wave 64x64 out
    int lrow = lane & 15;
    int lch  = lane >> 4;               // quarter index 0..3

    const ushort* pb = p2 + (size_t)b * NCH * LP * 8;
    int ar0 = tr * 128 + wr * 64;       // i rows (A fragments)
    int br0 = tc * 128 + wc * 64;       // j rows (B fragments)

    f32x4 acc[4][4] = {};
    #pragma unroll
    for (int ks = 0; ks < 3; ++ks) {
        const ushort* pk = pb + (size_t)(ks * 4 + lch) * LP * 8;  // chunk plane
        bf16x8 af[4], bfr[4];
        #pragma unroll
        for (int m = 0; m < 4; ++m)
            af[m] = *(const bf16x8*)&pk[(size_t)(ar0 + m * 16 + lrow) * 8];
        #pragma unroll
        for (int n = 0; n < 4; ++n)
            bfr[n] = *(const bf16x8*)&pk[(size_t)(br0 + n * 16 + lrow) * 8];
        #pragma unroll
        for (int m = 0; m < 4; ++m)
            #pragma unroll
            for (int n = 0; n < 4; ++n)
                acc[m][n] = __builtin_amdgcn_mfma_f32_16x16x32_bf16(af[m], bfr[n], acc[m][n], 0, 0, 0);
    }

    float inv = 1.0f / sqrtf(__uint_as_float(maxbits[b]));
    float* ob = out + (size_t)b * LP * LP;

    // Out rows j = br0 + n*16 + (lane&15); out cols i = ar0 + m*16 + lch*4 + reg.
    // Stream one n-stripe (16 j-rows x 64 i-cols) at a time through LDS;
    // alternate buffers so the next stripe's writes don't WAR-stall on this
    // stripe's reads.
    #pragma unroll
    for (int n = 0; n < 4; ++n) {
        float* Wp = &W[w][n & 1][0][0];
        // scatter fragments into swizzled LDS: slot' = slot ^ row
        #pragma unroll
        for (int m = 0; m < 4; ++m) {
            int sl = (m * 4 + lch) ^ lrow;         // 16B slot 0..15, swizzled
            f32x4 v;
            #pragma unroll
            for (int r = 0; r < 4; ++r) {
                float s = acc[m][n][r] * inv;
                v[r] = 1.0f / (1.0f + __expf(-s));
            }
            *(f32x4*)&Wp[lrow * 64 + sl * 4] = v;
        }
        // gather rows linearly; 4 rows x 256B full-line runs per store instr
        #pragma unroll
        for (int k = 0; k < 4; ++k) {
            int jr = k * 4 + lch;                  // local j-row 0..15
            int sl = lrow ^ jr;                    // inverse swizzle
            f32x4 v = *(const f32x4*)&Wp[jr * 64 + sl * 4];
            int j = br0 + n * 16 + jr;
            int i = ar0 + lrow * 4;
            __builtin_nontemporal_store(v, (f32x4*)&ob[(size_t)j * LP + i]);
        }
    }
}

extern "C" void kernel_launch(void* const* d_in, const int* in_sizes, int n_in,
                              void* d_out, int out_size, void* d_ws, size_t ws_size,
                              hipStream_t stream) {
    const float* x = (const float*)d_in[0];
    float* out = (float*)d_out;

    // ws layout: p2 bf16 blocked [NB][12][4096][8] (3.15 MB), then maxbits[4].
    ushort* p2 = (ushort*)d_ws;
    unsigned* maxbits = (unsigned*)((char*)d_ws + (size_t)NB * NCH * LP * 16);

    hipMemsetAsync(maxbits, 0, NB * sizeof(unsigned), stream);   // capture-legal
    norm_kernel<<<(NB * LP) / 4, 256, 0, stream>>>(x, maxbits);
    patch_kernel<<<dim3(LP / 256, NCH, NB), 256, 0, stream>>>(x, p2);
    gemm_kernel<<<dim3(32, 32, NB), 256, 0, stream>>>(p2, maxbits, out);
}

// Round 11
// 64.646 us; speedup vs baseline: 2.1665x; 1.7093x over previous
//
#include <hip/hip_runtime.h>
#include <hip/hip_bf16.h>

// Problem constants
#define NB   4      // batch
#define CCH  3      // channels
#define HW   320    // height == width
#define KS   5      // kernel/stride
#define LP   4096   // patches per batch (64*64)
#define KD   75     // c*k*k
#define NCH  12     // 16B chunks per patch row (96 bf16 = 12 x 8)

typedef __attribute__((ext_vector_type(4))) float f32x4;
typedef __attribute__((ext_vector_type(8))) short bf16x8;

__device__ __forceinline__ ushort f2bf(float v) {
    __hip_bfloat16 h = __float2bfloat16(v);
    return __builtin_bit_cast(ushort, h);
}

// Kernel 1: per-patch sumsq from x (fp32); per-block (4-patch) max written with
// a PLAIN store to blockmax[blockIdx.x]. No atomics, no memset, deterministic.
__global__ __launch_bounds__(256) void norm_kernel(const float* __restrict__ x,
                                                   float* __restrict__ blockmax) {
    int tid  = threadIdx.x;
    int lane = tid & 63;
    int pid  = blockIdx.x * 4 + (tid >> 6);   // 0..16383
    int b    = pid >> 12;
    int pp   = pid & 4095;
    int ph   = pp >> 6, pw = pp & 63;
    const float* xb = x + (size_t)b * (CCH * HW * HW);
    int row0 = ph * KS, col0 = pw * KS;

    float ss = 0.f;
    for (int k = lane; k < KD; k += 64) {
        int c = k / 25, rem = k % 25;
        int ki = rem / 5, kj = rem % 5;
        float v = xb[(c * HW + row0 + ki) * HW + col0 + kj];
        ss += v * v;
    }
    for (int off = 32; off; off >>= 1) ss += __shfl_xor(ss, off, 64);

    __shared__ float sm[4];
    if (lane == 0) sm[tid >> 6] = ss;
    __syncthreads();
    if (tid == 0)
        blockmax[blockIdx.x] = fmaxf(fmaxf(sm[0], sm[1]), fmaxf(sm[2], sm[3]));
}

// Kernel 1b: per-batch reduce of 1024 block maxima -> invmax[b] = 1/sqrt(max)
__global__ __launch_bounds__(256) void reduce_kernel(const float* __restrict__ blockmax,
                                                     float* __restrict__ invmax) {
    int b = blockIdx.x;
    float m = 0.f;
    for (int i = threadIdx.x; i < 1024; i += 256) m = fmaxf(m, blockmax[b * 1024 + i]);
    for (int off = 32; off; off >>= 1) m = fmaxf(m, __shfl_xor(m, off, 64));
    __shared__ float sm[4];
    if ((threadIdx.x & 63) == 0) sm[threadIdx.x >> 6] = m;
    __syncthreads();
    if (threadIdx.x == 0)
        invmax[b] = 1.0f / sqrtf(fmaxf(fmaxf(sm[0], sm[1]), fmaxf(sm[2], sm[3])));
}

// Kernel 2: build bf16 patch matrix in fragment-blocked layout
// p2[b][chunk][row] of 16B (8 bf16): chunk c holds patch cols 8c..8c+7
// (zero-padded past KD=75). Fully written every call (chunks 10,11 = zeros).
__global__ __launch_bounds__(256) void patch_kernel(const float* __restrict__ x,
                                                    ushort* __restrict__ p2) {
    int tid = threadIdx.x;
    int r   = blockIdx.x * 256 + tid;    // patch row 0..4095
    int c   = blockIdx.y;                // chunk 0..11
    int b   = blockIdx.z;
    int ph = r >> 6, pw = r & 63;
    const float* xb = x + (size_t)b * (CCH * HW * HW);

    bf16x8 v = {};
    if (c < 10) {
        #pragma unroll
        for (int j = 0; j < 8; ++j) {
            int k = c * 8 + j;
            float f = 0.f;
            if (k < KD) {
                int ch = k / 25, rem = k % 25;
                int ki = rem / 5, kj = rem % 5;
                f = xb[(ch * HW + ph * KS + ki) * HW + pw * KS + kj];
            }
            v[j] = (short)f2bf(f);
        }
    }
    *(bf16x8*)&p2[((size_t)(b * NCH + c) * LP + r) * 8] = v;
}

// Kernel 3: C = sigmoid((P P^T)/sqrt(max)), 256-col x 64-row OUTPUT tile per
// block (out row = j = B-side, out col = i = A-side; symmetric-transpose trick,
// bit-identical). 4 waves side-by-side on i; each wave 64x64 = 4x4 fragments,
// K=96 in 3 steps, fragments loaded directly from blocked p2 (L2-resident).
// Epilogue: BLOCK-level LDS restage (32KB, 2 phases of 32 j-rows, XOR-swizzled,
// bank-conflict-free at b128 baseline) -> every global store instruction
// writes ONE contiguous 1024B-aligned 1024B run (full 64-lane row segment),
// matching the harness fill's per-instruction pattern.
__global__ __launch_bounds__(256) void gemm_kernel(const ushort* __restrict__ p2,
                                                   const float* __restrict__ invmax,
                                                   float* __restrict__ out) {
    __shared__ float W[32][256];       // 32 KB restage buffer

    int b  = blockIdx.z;
    int ti = blockIdx.x;   // i-tile 0..15 (fast dim: sweeps cols in a j-band)
    int tj = blockIdx.y;   // j-tile 0..63
    int tid = threadIdx.x;
    int lane = tid & 63;
    int w    = tid >> 6;
    int lrow = lane & 15;
    int lch  = lane >> 4;

    const ushort* pb = p2 + (size_t)b * NCH * LP * 8;
    int i0 = ti * 256 + w * 64;         // this wave's i-rows (A side, out cols)
    int j0 = tj * 64;                   // block's j-rows (B side, out rows)

    f32x4 acc[4][4] = {};
    #pragma unroll
    for (int ks = 0; ks < 3; ++ks) {
        const ushort* pk = pb + (size_t)(ks * 4 + lch) * LP * 8;  // chunk plane
        bf16x8 af[4], bfr[4];
        #pragma unroll
        for (int m = 0; m < 4; ++m)
            af[m] = *(const bf16x8*)&pk[(size_t)(i0 + m * 16 + lrow) * 8];
        #pragma unroll
        for (int n = 0; n < 4; ++n)
            bfr[n] = *(const bf16x8*)&pk[(size_t)(j0 + n * 16 + lrow) * 8];
        #pragma unroll
        for (int m = 0; m < 4; ++m)
            #pragma unroll
            for (int n = 0; n < 4; ++n)
                acc[m][n] = __builtin_amdgcn_mfma_f32_16x16x32_bf16(af[m], bfr[n], acc[m][n], 0, 0, 0);
    }

    float inv = invmax[b];
    float* ob = out + (size_t)b * LP * LP;

    // D frag (m,n): out row j = j0 + n*16 + (lane&15); out col i = i0 + m*16
    // + lch*4 + reg (4 consecutive). Two phases, 32 j-rows each.
    #pragma unroll
    for (int h = 0; h < 2; ++h) {
        if (h) __syncthreads();         // WAR: previous phase fully read
        #pragma unroll
        for (int np = 0; np < 2; ++np) {
            int n  = h * 2 + np;
            int jr = np * 16 + lrow;               // row 0..31 within phase
            #pragma unroll
            for (int m = 0; m < 4; ++m) {
                // logical 16B slot = w*16 + m*4 + lch; XOR low bits with jr
                int sl = w * 16 + (((m * 4 + lch) ^ (jr & 7)) & 15);
                f32x4 v;
                #pragma unroll
                for (int r = 0; r < 4; ++r) {
                    float s = acc[m][n][r] * inv;
                    v[r] = 1.0f / (1.0f + __expf(-s));
                }
                *(f32x4*)&W[jr][sl * 4] = v;
            }
        }
        __syncthreads();
        // each wave stores 8 rows; one instruction = 64 lanes x 16B = 1024B
        // contiguous, 1024B-aligned (row base = multiple of 16KB + ti*1024B)
        #pragma unroll
        for (int r8 = 0; r8 < 8; ++r8) {
            int row = w * 8 + r8;                  // 0..31
            f32x4 v = *(const f32x4*)&W[row][(lane ^ (row & 7)) * 4];
            *(f32x4*)&ob[(size_t)(j0 + h * 32 + row) * LP + ti * 256 + lane * 4] = v;
        }
    }
}

extern "C" void kernel_launch(void* const* d_in, const int* in_sizes, int n_in,
                              void* d_out, int out_size, void* d_ws, size_t ws_size,
                              hipStream_t stream) {
    const float* x = (const float*)d_in[0];
    float* out = (float*)d_out;

    // ws layout: p2 bf16 blocked [NB][12][4096][8] (3.15 MB), blockmax f32[4096],
    // invmax f32[4]. Everything written-before-read with plain stores each call.
    ushort* p2 = (ushort*)d_ws;
    float* blockmax = (float*)((char*)d_ws + (size_t)NB * NCH * LP * 16);
    float* invmax = blockmax + 4096;

    norm_kernel<<<(NB * LP) / 4, 256, 0, stream>>>(x, blockmax);
    patch_kernel<<<dim3(LP / 256, NCH, NB), 256, 0, stream>>>(x, p2);
    reduce_kernel<<<NB, 256, 0, stream>>>(blockmax, invmax);
    gemm_kernel<<<dim3(16, 64, NB), 256, 0, stream>>>(p2, invmax, out);
}

// Round 12
// 62.744 us; speedup vs baseline: 2.2322x; 1.0303x over previous
//
#include <hip/hip_runtime.h>
#include <hip/hip_bf16.h>

// Problem constants
#define NB   4      // batch
#define CCH  3      // channels
#define HW   320    // height == width
#define KS   5      // kernel/stride
#define LP   4096   // patches per batch (64*64)
#define KD   75     // c*k*k
#define NCH  12     // 16B chunks per patch row (96 bf16 = 12 x 8)

typedef __attribute__((ext_vector_type(4))) float f32x4;
typedef __attribute__((ext_vector_type(8))) short bf16x8;

__device__ __forceinline__ ushort f2bf(float v) {
    __hip_bfloat16 h = __float2bfloat16(v);
    return __builtin_bit_cast(ushort, h);
}

// Kernel 1: build bf16 patch matrix in fragment-blocked layout
// p2[b][chunk][row] of 16B (8 bf16): chunk c holds patch cols 8c..8c+7
// (zero-padded past KD=75). Fully written every call (chunks 10,11 = zeros).
__global__ __launch_bounds__(256) void patch_kernel(const float* __restrict__ x,
                                                    ushort* __restrict__ p2) {
    int tid = threadIdx.x;
    int r   = blockIdx.x * 256 + tid;    // patch row 0..4095
    int c   = blockIdx.y;                // chunk 0..11
    int b   = blockIdx.z;
    int ph = r >> 6, pw = r & 63;
    const float* xb = x + (size_t)b * (CCH * HW * HW);

    bf16x8 v = {};
    if (c < 10) {
        #pragma unroll
        for (int j = 0; j < 8; ++j) {
            int k = c * 8 + j;
            float f = 0.f;
            if (k < KD) {
                int ch = k / 25, rem = k % 25;
                int ki = rem / 5, kj = rem % 5;
                f = xb[(ch * HW + ph * KS + ki) * HW + pw * KS + kj];
            }
            v[j] = (short)f2bf(f);
        }
    }
    *(bf16x8*)&p2[((size_t)(b * NCH + c) * LP + r) * 8] = v;
}

// Kernel 2: per-patch sumsq from the BLOCKED bf16 p2 (fully coalesced 16B
// loads; bf16 rounding adds ~0.05% rel err to max||p|| — well within the
// 2e-2 output threshold). One patch per thread; block max -> plain store.
__global__ __launch_bounds__(256) void normb_kernel(const ushort* __restrict__ p2,
                                                    float* __restrict__ blockmax) {
    int b = blockIdx.y;
    int r = blockIdx.x * 256 + threadIdx.x;     // patch row
    const ushort* pb = p2 + (size_t)b * NCH * LP * 8;

    float ss = 0.f;
    #pragma unroll
    for (int c = 0; c < 10; ++c) {              // chunks 10,11 are zeros
        bf16x8 v = *(const bf16x8*)&pb[((size_t)c * LP + r) * 8];
        #pragma unroll
        for (int j = 0; j < 8; ++j) {
            float f = __uint_as_float(((unsigned)(ushort)v[j]) << 16);
            ss = fmaf(f, f, ss);
        }
    }
    for (int off = 32; off; off >>= 1) ss = fmaxf(ss, __shfl_xor(ss, off, 64));
    __shared__ float sm[4];
    if ((threadIdx.x & 63) == 0) sm[threadIdx.x >> 6] = ss;
    __syncthreads();
    if (threadIdx.x == 0)
        blockmax[b * 16 + blockIdx.x] =
            fmaxf(fmaxf(sm[0], sm[1]), fmaxf(sm[2], sm[3]));
}

// Kernel 2b: per-batch reduce of 16 block maxima -> invmax[b] = 1/sqrt(max)
__global__ __launch_bounds__(64) void reduce_kernel(const float* __restrict__ blockmax,
                                                    float* __restrict__ invmax) {
    int b = blockIdx.x;
    if (threadIdx.x == 0) {
        float m = 0.f;
        #pragma unroll
        for (int i = 0; i < 16; ++i) m = fmaxf(m, blockmax[b * 16 + i]);
        invmax[b] = 1.0f / sqrtf(m);
    }
}

// Kernel 3: C = sigmoid((P P^T)/sqrt(max)), 256-col x 64-row OUTPUT tile per
// block (out row = j = B-side, out col = i = A-side; symmetric-transpose trick,
// bit-identical). 4 waves side-by-side on i; each wave 64x64 = 4x4 fragments,
// K=96 in 3 steps, fragments loaded directly from blocked p2 (L2-resident).
// Epilogue: BLOCK-level LDS restage (32KB, 2 phases of 32 j-rows, XOR-swizzled)
// -> every global store instruction writes ONE contiguous 1024B-aligned 1024B
// run; stores NONTEMPORAL so the 256MB stream doesn't evict p2 from L2.
__global__ __launch_bounds__(256) void gemm_kernel(const ushort* __restrict__ p2,
                                                   const float* __restrict__ invmax,
                                                   float* __restrict__ out) {
    __shared__ float W[32][256];       // 32 KB restage buffer

    int b  = blockIdx.z;
    int ti = blockIdx.x;   // i-tile 0..15 (fast dim: sweeps cols in a j-band)
    int tj = blockIdx.y;   // j-tile 0..63
    int tid = threadIdx.x;
    int lane = tid & 63;
    int w    = tid >> 6;
    int lrow = lane & 15;
    int lch  = lane >> 4;

    const ushort* pb = p2 + (size_t)b * NCH * LP * 8;
    int i0 = ti * 256 + w * 64;         // this wave's i-rows (A side, out cols)
    int j0 = tj * 64;                   // block's j-rows (B side, out rows)

    f32x4 acc[4][4] = {};
    #pragma unroll
    for (int ks = 0; ks < 3; ++ks) {
        const ushort* pk = pb + (size_t)(ks * 4 + lch) * LP * 8;  // chunk plane
        bf16x8 af[4], bfr[4];
        #pragma unroll
        for (int m = 0; m < 4; ++m)
            af[m] = *(const bf16x8*)&pk[(size_t)(i0 + m * 16 + lrow) * 8];
        #pragma unroll
        for (int n = 0; n < 4; ++n)
            bfr[n] = *(const bf16x8*)&pk[(size_t)(j0 + n * 16 + lrow) * 8];
        #pragma unroll
        for (int m = 0; m < 4; ++m)
            #pragma unroll
            for (int n = 0; n < 4; ++n)
                acc[m][n] = __builtin_amdgcn_mfma_f32_16x16x32_bf16(af[m], bfr[n], acc[m][n], 0, 0, 0);
    }

    float inv = invmax[b];
    float* ob = out + (size_t)b * LP * LP;

    // D frag (m,n): out row j = j0 + n*16 + (lane&15); out col i = i0 + m*16
    // + lch*4 + reg (4 consecutive). Two phases, 32 j-rows each.
    #pragma unroll
    for (int h = 0; h < 2; ++h) {
        if (h) __syncthreads();         // WAR: previous phase fully read
        #pragma unroll
        for (int np = 0; np < 2; ++np) {
            int n  = h * 2 + np;
            int jr = np * 16 + lrow;               // row 0..31 within phase
            #pragma unroll
            for (int m = 0; m < 4; ++m) {
                // logical 16B slot = w*16 + m*4 + lch; XOR low bits with jr
                int sl = w * 16 + (((m * 4 + lch) ^ (jr & 7)) & 15);
                f32x4 v;
                #pragma unroll
                for (int r = 0; r < 4; ++r) {
                    float s = acc[m][n][r] * inv;
                    v[r] = 1.0f / (1.0f + __expf(-s));
                }
                *(f32x4*)&W[jr][sl * 4] = v;
            }
        }
        __syncthreads();
        // each wave stores 8 rows; one instruction = 64 lanes x 16B = 1024B
        // contiguous, 1024B-aligned (row base = multiple of 16KB + ti*1024B)
        #pragma unroll
        for (int r8 = 0; r8 < 8; ++r8) {
            int row = w * 8 + r8;                  // 0..31
            f32x4 v = *(const f32x4*)&W[row][(lane ^ (row & 7)) * 4];
            __builtin_nontemporal_store(v,
                (f32x4*)&ob[(size_t)(j0 + h * 32 + row) * LP + ti * 256 + lane * 4]);
        }
    }
}

extern "C" void kernel_launch(void* const* d_in, const int* in_sizes, int n_in,
                              void* d_out, int out_size, void* d_ws, size_t ws_size,
                              hipStream_t stream) {
    const float* x = (const float*)d_in[0];
    float* out = (float*)d_out;

    // ws layout: p2 bf16 blocked [NB][12][4096][8] (3.15 MB), blockmax f32[64],
    // invmax f32[4]. Everything written-before-read with plain stores each call.
    ushort* p2 = (ushort*)d_ws;
    float* blockmax = (float*)((char*)d_ws + (size_t)NB * NCH * LP * 16);
    float* invmax = blockmax + 64;

    patch_kernel<<<dim3(LP / 256, NCH, NB), 256, 0, stream>>>(x, p2);
    normb_kernel<<<dim3(LP / 256, NB), 256, 0, stream>>>(p2, blockmax);
    reduce_kernel<<<NB, 64, 0, stream>>>(blockmax, invmax);
    gemm_kernel<<<dim3(16, 64, NB), 256, 0, stream>>>(p2, invmax, out);
}

// Round 13
// 61.881 us; speedup vs baseline: 2.2633x; 1.0139x over previous
//
#include <hip/hip_runtime.h>
#include <hip/hip_bf16.h>

// Problem constants
#define NB   4      // batch
#define CCH  3      // channels
#define HW   320    // height == width
#define KS   5      // kernel/stride
#define LP   4096   // patches per batch (64*64)
#define KD   75     // c*k*k
#define NCH  12     // 16B chunks per patch row (96 bf16 = 12 x 8)

typedef __attribute__((ext_vector_type(4))) float f32x4;
typedef __attribute__((ext_vector_type(8))) short bf16x8;

__device__ __forceinline__ ushort f2bf(float v) {
    __hip_bfloat16 h = __float2bfloat16(v);
    return __builtin_bit_cast(ushort, h);
}

// Kernel 1: build bf16 patch matrix in fragment-blocked layout
// p2[b][chunk][row] of 16B (8 bf16): chunk c holds patch cols 8c..8c+7
// (zero-padded past KD=75). Fully written every call (chunks 10,11 = zeros).
__global__ __launch_bounds__(256) void patch_kernel(const float* __restrict__ x,
                                                    ushort* __restrict__ p2) {
    int tid = threadIdx.x;
    int r   = blockIdx.x * 256 + tid;    // patch row 0..4095
    int c   = blockIdx.y;                // chunk 0..11
    int b   = blockIdx.z;
    int ph = r >> 6, pw = r & 63;
    const float* xb = x + (size_t)b * (CCH * HW * HW);

    bf16x8 v = {};
    if (c < 10) {
        #pragma unroll
        for (int j = 0; j < 8; ++j) {
            int k = c * 8 + j;
            float f = 0.f;
            if (k < KD) {
                int ch = k / 25, rem = k % 25;
                int ki = rem / 5, kj = rem % 5;
                f = xb[(ch * HW + ph * KS + ki) * HW + pw * KS + kj];
            }
            v[j] = (short)f2bf(f);
        }
    }
    *(bf16x8*)&p2[((size_t)(b * NCH + c) * LP + r) * 8] = v;
}

// Kernel 2: per-patch sumsq from the BLOCKED bf16 p2 (fully coalesced 16B
// loads; bf16 rounding adds ~0.05% rel err to max||p|| — well within the
// 2e-2 output threshold). One patch per thread; block max -> plain store.
__global__ __launch_bounds__(256) void normb_kernel(const ushort* __restrict__ p2,
                                                    float* __restrict__ blockmax) {
    int b = blockIdx.y;
    int r = blockIdx.x * 256 + threadIdx.x;     // patch row
    const ushort* pb = p2 + (size_t)b * NCH * LP * 8;

    float ss = 0.f;
    #pragma unroll
    for (int c = 0; c < 10; ++c) {              // chunks 10,11 are zeros
        bf16x8 v = *(const bf16x8*)&pb[((size_t)c * LP + r) * 8];
        #pragma unroll
        for (int j = 0; j < 8; ++j) {
            float f = __uint_as_float(((unsigned)(ushort)v[j]) << 16);
            ss = fmaf(f, f, ss);
        }
    }
    for (int off = 32; off; off >>= 1) ss = fmaxf(ss, __shfl_xor(ss, off, 64));
    __shared__ float sm[4];
    if ((threadIdx.x & 63) == 0) sm[threadIdx.x >> 6] = ss;
    __syncthreads();
    if (threadIdx.x == 0)
        blockmax[b * 16 + blockIdx.x] =
            fmaxf(fmaxf(sm[0], sm[1]), fmaxf(sm[2], sm[3]));
}

// Kernel 3: C = sigmoid((P P^T)/sqrt(max)), 256-col x 64-row OUTPUT tile per
// block (out row = j = B-side, out col = i = A-side; symmetric-transpose trick,
// bit-identical). 4 waves side-by-side on i; each wave 64x64 = 4x4 fragments,
// K=96 in 3 steps, fragments loaded directly from blocked p2 (L2-resident).
// Per-block invmax fold from blockmax[16] (replaces a reduce launch).
// Sigmoid uses __builtin_amdgcn_rcpf (1 quarter-rate op) instead of the
// full-precision divide sequence (~8 VALU ops) — rel err ~1e-7 << 2e-2.
// Epilogue: BLOCK-level LDS restage (32KB, 2 phases of 32 j-rows, XOR-swizzled)
// -> every global store instruction writes ONE contiguous 1024B-aligned 1024B
// run; stores NONTEMPORAL so the 256MB stream doesn't evict p2 from L2.
__global__ __launch_bounds__(256) void gemm_kernel(const ushort* __restrict__ p2,
                                                   const float* __restrict__ blockmax,
                                                   float* __restrict__ out) {
    __shared__ float W[32][256];       // 32 KB restage buffer

    int b  = blockIdx.z;
    int ti = blockIdx.x;   // i-tile 0..15 (fast dim: sweeps cols in a j-band)
    int tj = blockIdx.y;   // j-tile 0..63
    int tid = threadIdx.x;
    int lane = tid & 63;
    int w    = tid >> 6;
    int lrow = lane & 15;
    int lch  = lane >> 4;

    const ushort* pb = p2 + (size_t)b * NCH * LP * 8;
    int i0 = ti * 256 + w * 64;         // this wave's i-rows (A side, out cols)
    int j0 = tj * 64;                   // block's j-rows (B side, out rows)

    f32x4 acc[4][4] = {};
    #pragma unroll
    for (int ks = 0; ks < 3; ++ks) {
        const ushort* pk = pb + (size_t)(ks * 4 + lch) * LP * 8;  // chunk plane
        bf16x8 af[4], bfr[4];
        #pragma unroll
        for (int m = 0; m < 4; ++m)
            af[m] = *(const bf16x8*)&pk[(size_t)(i0 + m * 16 + lrow) * 8];
        #pragma unroll
        for (int n = 0; n < 4; ++n)
            bfr[n] = *(const bf16x8*)&pk[(size_t)(j0 + n * 16 + lrow) * 8];
        #pragma unroll
        for (int m = 0; m < 4; ++m)
            #pragma unroll
            for (int n = 0; n < 4; ++n)
                acc[m][n] = __builtin_amdgcn_mfma_f32_16x16x32_bf16(af[m], bfr[n], acc[m][n], 0, 0, 0);
    }

    // fold per-batch max from the 16 block maxima (uniform; ~100 cycles)
    float mx = 0.f;
    #pragma unroll
    for (int i = 0; i < 16; ++i) mx = fmaxf(mx, blockmax[b * 16 + i]);
    float inv = 1.0f / sqrtf(mx);
    float* ob = out + (size_t)b * LP * LP;

    // D frag (m,n): out row j = j0 + n*16 + (lane&15); out col i = i0 + m*16
    // + lch*4 + reg (4 consecutive). Two phases, 32 j-rows each.
    #pragma unroll
    for (int h = 0; h < 2; ++h) {
        if (h) __syncthreads();         // WAR: previous phase fully read
        #pragma unroll
        for (int np = 0; np < 2; ++np) {
            int n  = h * 2 + np;
            int jr = np * 16 + lrow;               // row 0..31 within phase
            #pragma unroll
            for (int m = 0; m < 4; ++m) {
                // logical 16B slot = w*16 + m*4 + lch; XOR low bits with jr
                int sl = w * 16 + (((m * 4 + lch) ^ (jr & 7)) & 15);
                f32x4 v;
                #pragma unroll
                for (int r = 0; r < 4; ++r) {
                    float s = acc[m][n][r] * inv;
                    v[r] = __builtin_amdgcn_rcpf(1.0f + __expf(-s));
                }
                *(f32x4*)&W[jr][sl * 4] = v;
            }
        }
        __syncthreads();
        // each wave stores 8 rows; one instruction = 64 lanes x 16B = 1024B
        // contiguous, 1024B-aligned (row base = multiple of 16KB + ti*1024B)
        #pragma unroll
        for (int r8 = 0; r8 < 8; ++r8) {
            int row = w * 8 + r8;                  // 0..31
            f32x4 v = *(const f32x4*)&W[row][(lane ^ (row & 7)) * 4];
            __builtin_nontemporal_store(v,
                (f32x4*)&ob[(size_t)(j0 + h * 32 + row) * LP + ti * 256 + lane * 4]);
        }
    }
}

extern "C" void kernel_launch(void* const* d_in, const int* in_sizes, int n_in,
                              void* d_out, int out_size, void* d_ws, size_t ws_size,
                              hipStream_t stream) {
    const float* x = (const float*)d_in[0];
    float* out = (float*)d_out;

    // ws layout: p2 bf16 blocked [NB][12][4096][8] (3.15 MB), blockmax f32[64].
    // Everything written-before-read with plain stores each call.
    ushort* p2 = (ushort*)d_ws;
    float* blockmax = (float*)((char*)d_ws + (size_t)NB * NCH * LP * 16);

    patch_kernel<<<dim3(LP / 256, NCH, NB), 256, 0, stream>>>(x, p2);
    normb_kernel<<<dim3(LP / 256, NB), 256, 0, stream>>>(p2, blockmax);
    gemm_kernel<<<dim3(16, 64, NB), 256, 0, stream>>>(p2, blockmax, out);
}